// Round 1
// baseline (170.354 us; speedup 1.0000x reference)
//
#include <hip/hip_runtime.h>
#include <math.h>

// DynamicViewSampler on MI355X — fp32 baseline, valid-length-aware.
//
// out[b,v,d] = sum_l m[b,v,l] * v_pad[b,l,d] / (sum_l m[b,v,l] + 1e-6)
// m[b,v,l] = exp(-20 * ||centers[b,v] - coord(l)||^2) for l < v_len[b], else 0
//
// Kernel 1: per-(batch, D-chunk, L-chunk) partial GEMM with LDS staging,
//           m computed in-kernel. Only valid rows (l < v_len) are read/computed.
// Kernel 2: reduce K partials + divide by denominator.

constexpr int VV  = 64;   // NUM_VIEWS
constexpr int DC  = 256;  // D columns per block
constexpr int TL  = 32;   // L rows per LDS tile
constexpr int NTH = 256;  // threads per block

__global__ __launch_bounds__(NTH)
void dvs_partial(const float* __restrict__ v_pad,
                 const int*   __restrict__ v_len,
                 const int*   __restrict__ grid_thws,
                 const float* __restrict__ centers,
                 float*       __restrict__ num_part,   // [B][K][V][D]
                 float*       __restrict__ den_part,   // [B][K][V]
                 int B, int L, int D, int K)
{
    const int k   = blockIdx.x;   // L-chunk
    const int dcb = blockIdx.y;   // D-chunk
    const int b   = blockIdx.z;   // batch
    const int tid = threadIdx.x;
    const int d0  = dcb * DC;

    __shared__ float  sv[TL][DC];   // 32 KB
    __shared__ float  sm[TL][VV];   // 8 KB (reused for denominator reduce)
    __shared__ float2 scent[VV];

    // per-batch geometry (matches jnp: round-half-even, ceil, all f32)
    const int   Lv = v_len[b];
    const float Hf = (float)grid_thws[b * 3 + 1];
    const float Wf = (float)grid_thws[b * 3 + 2];
    const float sq = sqrtf((float)Lv * (Wf / Hf));
    int W_eff = (int)rintf(sq);                          if (W_eff < 1) W_eff = 1;
    int H_eff = (int)ceilf((float)Lv / (float)W_eff);    if (H_eff < 1) H_eff = 1;
    const float invW = 1.0f / (float)W_eff;
    const float invH = 1.0f / (float)H_eff;

    if (tid < VV) scent[tid] = ((const float2*)centers)[(size_t)b * VV + tid];

    // split the VALID length evenly across K chunks (load balance)
    const int chunk = (Lv + K - 1) / K;
    const int l0 = k * chunk;
    const int l1 = min(l0 + chunk, Lv);

    const int dg = tid & 15;    // 16 d-groups of 16 columns
    const int vg = tid >> 4;    // 16 v-groups of 4 views
    const int lm = tid >> 3;    // m-staging: l row (0..31)
    const int vs = (tid & 7) * 8; // m-staging: 8 views starting here

    float4 acc[4][4];
#pragma unroll
    for (int i = 0; i < 4; ++i)
#pragma unroll
        for (int j = 0; j < 4; ++j) acc[i][j] = make_float4(0.f, 0.f, 0.f, 0.f);

    float den8[8];
#pragma unroll
    for (int j = 0; j < 8; ++j) den8[j] = 0.0f;

    __syncthreads();  // scent ready

    for (int lt = l0; lt < l1; lt += TL) {
        // ---- stage v_pad tile (coalesced float4, zero-pad past l1) ----
#pragma unroll
        for (int it = 0; it < 8; ++it) {
            const int lrow = it * 4 + (tid >> 6);
            const int c4   = tid & 63;
            const int l    = lt + lrow;
            float4 val = make_float4(0.f, 0.f, 0.f, 0.f);
            if (l < l1)
                val = ((const float4*)(v_pad + ((size_t)b * L + l) * (size_t)D + d0))[c4];
            ((float4*)&sv[lrow][0])[c4] = val;
        }
        // ---- compute m tile: thread -> (row lm, views vs..vs+7) ----
        {
            const int l = lt + lm;
            if (l < l1) {
                const float x = (float)(l % W_eff) * invW;
                const float y = (float)(l / W_eff) * invH;
#pragma unroll
                for (int j = 0; j < 8; ++j) {
                    const float dx = scent[vs + j].x - x;
                    const float dy = scent[vs + j].y - y;
                    const float m  = __expf(-20.0f * (dx * dx + dy * dy));
                    sm[lm][vs + j] = m;
                    den8[j] += m;
                }
            } else {
#pragma unroll
                for (int j = 0; j < 8; ++j) sm[lm][vs + j] = 0.0f;
            }
        }
        __syncthreads();
        // ---- register-blocked accumulate: 4 views x 16 cols per thread ----
#pragma unroll 8
        for (int ll = 0; ll < TL; ++ll) {
            const float4 mv = ((const float4*)&sm[ll][0])[vg];
            const float  mvc[4] = { mv.x, mv.y, mv.z, mv.w };
            float4 vvs[4];
#pragma unroll
            for (int j = 0; j < 4; ++j)
                vvs[j] = ((const float4*)&sv[ll][0])[dg * 4 + j];
#pragma unroll
            for (int i = 0; i < 4; ++i) {
#pragma unroll
                for (int j = 0; j < 4; ++j) {
                    acc[i][j].x = fmaf(mvc[i], vvs[j].x, acc[i][j].x);
                    acc[i][j].y = fmaf(mvc[i], vvs[j].y, acc[i][j].y);
                    acc[i][j].z = fmaf(mvc[i], vvs[j].z, acc[i][j].z);
                    acc[i][j].w = fmaf(mvc[i], vvs[j].w, acc[i][j].w);
                }
            }
        }
        __syncthreads();
    }

    // ---- denominator: reduce den8 across threads via sm (deterministic) ----
#pragma unroll
    for (int j = 0; j < 8; ++j) sm[lm][vs + j] = den8[j];
    __syncthreads();
    if (dcb == 0 && tid < VV) {
        float s = 0.0f;
#pragma unroll
        for (int r = 0; r < TL; ++r) s += sm[r][tid];
        den_part[((size_t)b * K + k) * VV + tid] = s;
    }

    // ---- write numerator partials ----
    float* base = num_part + ((size_t)b * K + k) * VV * (size_t)D;
#pragma unroll
    for (int i = 0; i < 4; ++i) {
        const int v = vg * 4 + i;
        float4* row = (float4*)(base + (size_t)v * D + d0);
#pragma unroll
        for (int j = 0; j < 4; ++j) row[dg * 4 + j] = acc[i][j];
    }
}

__global__ __launch_bounds__(256)
void dvs_reduce(const float* __restrict__ num_part,
                const float* __restrict__ den_part,
                float*       __restrict__ out,
                int B, int D, int K, int total)
{
    const int idx = blockIdx.x * 256 + threadIdx.x;
    if (idx >= total) return;
    const int d  = idx % D;
    const int bv = idx / D;
    const int b  = bv / VV;
    const int v  = bv - b * VV;

    float den = 1e-6f;
    float num = 0.0f;
    for (int k = 0; k < K; ++k) {
        den += den_part[((size_t)b * K + k) * VV + v];
        num += num_part[(((size_t)b * K + k) * VV + v) * (size_t)D + d];
    }
    out[idx] = num / den;
}

extern "C" void kernel_launch(void* const* d_in, const int* in_sizes, int n_in,
                              void* d_out, int out_size, void* d_ws, size_t ws_size,
                              hipStream_t stream)
{
    const float* v_pad     = (const float*)d_in[0];
    const int*   v_len     = (const int*)d_in[1];
    const int*   grid_thws = (const int*)d_in[2];
    const float* centers   = (const float*)d_in[3];
    float*       out       = (float*)d_out;

    const int B = in_sizes[1];
    const int V = VV;
    const int D = out_size / (B * V);
    const int L = in_sizes[0] / (B * D);

    // pick K (L-split) that fits in workspace
    int K = 8;
    const size_t per_k = ((size_t)B * V * D + (size_t)B * V) * sizeof(float);
    while (K > 1 && (size_t)K * per_k > ws_size) K >>= 1;

    float* num_part = (float*)d_ws;
    float* den_part = num_part + (size_t)B * K * V * D;

    dim3 grid1(K, D / DC, B);
    dvs_partial<<<grid1, NTH, 0, stream>>>(v_pad, v_len, grid_thws, centers,
                                           num_part, den_part, B, L, D, K);

    const int total = B * V * D;
    dvs_reduce<<<(total + 255) / 256, 256, 0, stream>>>(num_part, den_part, out,
                                                        B, D, K, total);
}

// Round 3
// 52.588 us; speedup vs baseline: 3.2394x; 3.2394x over previous
//
#include <hip/hip_runtime.h>
#include <math.h>
#include <stdint.h>

// DynamicViewSampler — bf16 MFMA, conservative operand paths.
// A = m (V=64 x K), packed into fragment order in LDS (plain b128 reads).
// B = v_pad tile staged row-major [l][d] bf16 (NO transpose);
//     fragments gathered with 8x ds_read_u16 (conflict-free stride ST=270).
// C = 16x16x32 bf16 MFMA, f32 accum; K-split partials reduced by kernel 2.

constexpr int VV      = 64;    // views (M)
constexpr int DC      = 256;   // D cols per block (N)
constexpr int KS      = 64;    // L rows per tile (two K=32 MFMA steps)
constexpr int NTH     = 256;
constexpr int ST      = 270;   // smB row stride in bf16 elements (bank-spread)
constexpr int SXY_MAX = 512;

typedef __attribute__((ext_vector_type(8))) short short8;
typedef __attribute__((ext_vector_type(4))) float f32x4;

static __device__ __forceinline__ unsigned short f2bf(float f) {
    unsigned u = __builtin_bit_cast(unsigned, f);
    u += 0x7fffu + ((u >> 16) & 1u);          // RNE
    return (unsigned short)(u >> 16);
}

__global__ __launch_bounds__(NTH)
void dvs_mfma(const float* __restrict__ v_pad, const int* __restrict__ v_len,
              const int* __restrict__ grid_thws, const float* __restrict__ centers,
              float* __restrict__ num_part,   // [B][K][V][D]
              float* __restrict__ den_part,   // [B][K][V]
              int B, int L, int D, int K)
{
    const int kblk = blockIdx.x, dcb = blockIdx.y, b = blockIdx.z;
    const int tid  = threadIdx.x;
    const int d0   = dcb * DC;
    const int lane = tid & 63;
    const int wave = tid >> 6;

    __shared__ __align__(16) unsigned short smA[512 * 8];   // [ks2][mf4][64][8] = 8 KB
    __shared__ __align__(16) unsigned short smB[KS][ST];    // ~33.8 KB
    __shared__ float2 sxy[SXY_MAX];                          // 4 KB
    __shared__ float  sden[4][VV];                           // 1 KB

    // ---- geometry (exact f32 replication of reference) ----
    const int   Lv = v_len[b];
    const float Hf = (float)grid_thws[b*3 + 1];
    const float Wf = (float)grid_thws[b*3 + 2];
    const float sq = sqrtf((float)Lv * (Wf / Hf));
    int W_eff = (int)rintf(sq);                       if (W_eff < 1) W_eff = 1;
    int H_eff = (int)ceilf((float)Lv / (float)W_eff); if (H_eff < 1) H_eff = 1;
    const float invW = 1.f / (float)W_eff, invH = 1.f / (float)H_eff;

    const int chunk = (Lv + K - 1) / K;
    const int l0 = kblk * chunk;
    const int l1 = min(l0 + chunk, Lv);

    // ---- A-compute role: thread -> view av, k-octet aq ----
    const int    av  = tid & 63;
    const int    aq  = tid >> 6;
    const float2 ctr = ((const float2*)centers)[(size_t)b * VV + av];
    const int    amf = av >> 4, ar = av & 15;
    float denacc = 0.f;

    // ---- B-staging role: thread -> d-quad d4, l-offset lq ----
    const int d4 = tid & 63;
    const int lq = tid >> 6;

    // ---- fragment-read role ----
    const int fcol = lane & 15, foct = lane >> 4;

    f32x4 acc[4][4];
#pragma unroll
    for (int i = 0; i < 4; ++i)
#pragma unroll
        for (int j = 0; j < 4; ++j) acc[i][j] = f32x4{0.f, 0.f, 0.f, 0.f};

    const float* vp_b = v_pad + (size_t)b * L * D + d0;

    for (int st = l0; st < l1; st += SXY_MAX) {
        const int st1 = min(st + SXY_MAX, l1);
        __syncthreads();                       // prior reads of sxy done
        for (int i = tid; i < st1 - st; i += NTH) {
            const int l   = st + i;
            const int row = l / W_eff;
            const int col = l - row * W_eff;
            sxy[i] = make_float2((float)col * invW, (float)row * invH);
        }
        __syncthreads();

        for (int lt = st; lt < st1; lt += KS) {
            // ---- issue global loads early ----
            float4 ld[16];
#pragma unroll
            for (int it = 0; it < 16; ++it) {
                const int l = lt + it * 4 + lq;
                ld[it] = make_float4(0.f, 0.f, 0.f, 0.f);
                if (l < st1)
                    ld[it] = *(const float4*)(vp_b + (size_t)l * D + d4 * 4);
            }
            __syncthreads();                   // prev-iter fragment reads done

            // ---- stage B row-major bf16: smB[l][d4*4 .. +3] ----
#pragma unroll
            for (int it = 0; it < 16; ++it) {
                const int lrow = it * 4 + lq;
                unsigned* w = (unsigned*)&smB[lrow][d4 * 4];
                unsigned p0 = (unsigned)f2bf(ld[it].x) | ((unsigned)f2bf(ld[it].y) << 16);
                unsigned p1 = (unsigned)f2bf(ld[it].z) | ((unsigned)f2bf(ld[it].w) << 16);
                w[0] = p0;
                w[1] = p1;
            }

            // ---- stage A: m packed directly into fragment order ----
#pragma unroll
            for (int ks = 0; ks < 2; ++ks) {
                union { unsigned short h[8]; short8 s; } ap;
#pragma unroll
                for (int j = 0; j < 8; ++j) {
                    const int kl = ks * 32 + aq * 8 + j;
                    const int l  = lt + kl;
                    float m = 0.f;
                    if (l < st1) {
                        const float2 xy = sxy[(lt - st) + kl];
                        const float dx = ctr.x - xy.x, dy = ctr.y - xy.y;
                        m = __expf(-20.f * (dx * dx + dy * dy));
                    }
                    denacc += m;
                    ap.h[j] = f2bf(m);
                }
                ((short8*)smA)[(ks * 4 + amf) * 64 + aq * 16 + ar] = ap.s;
            }
            __syncthreads();

            // ---- MFMA: 2 k-halves x 4 m-frags x 4 n-frags ----
#pragma unroll
            for (int ks = 0; ks < 2; ++ks) {
                short8 af[4];
#pragma unroll
                for (int mf = 0; mf < 4; ++mf)
                    af[mf] = ((const short8*)smA)[(ks * 4 + mf) * 64 + lane];

#pragma unroll
                for (int nf = 0; nf < 4; ++nf) {
                    const int colx  = wave * 64 + nf * 16 + fcol;
                    const int kbase = ks * 32 + foct * 8;
                    union { unsigned short h[8]; short8 s; } bf;
#pragma unroll
                    for (int j = 0; j < 8; ++j)
                        bf.h[j] = smB[kbase + j][colx];
#pragma unroll
                    for (int mf = 0; mf < 4; ++mf)
                        acc[mf][nf] = __builtin_amdgcn_mfma_f32_16x16x32_bf16(
                            af[mf], bf.s, acc[mf][nf], 0, 0, 0);
                }
            }
        }
    }

    // ---- denominator reduce (deterministic) ----
    sden[aq][av] = denacc;
    __syncthreads();
    if (dcb == 0 && tid < VV) {
        den_part[((size_t)b * K + kblk) * VV + tid] =
            sden[0][tid] + sden[1][tid] + sden[2][tid] + sden[3][tid];
    }

    // ---- numerator partials (C/D: col=lane&15, row=(lane>>4)*4+r) ----
    float* basep = num_part + ((size_t)b * K + kblk) * VV * (size_t)D + d0 + wave * 64;
#pragma unroll
    for (int mf = 0; mf < 4; ++mf) {
#pragma unroll
        for (int nf = 0; nf < 4; ++nf) {
            const int colx = nf * 16 + fcol;
            const int row0 = mf * 16 + foct * 4;
#pragma unroll
            for (int r = 0; r < 4; ++r)
                basep[(size_t)(row0 + r) * D + colx] = acc[mf][nf][r];
        }
    }
}

__global__ __launch_bounds__(256)
void dvs_reduce(const float* __restrict__ num_part,
                const float* __restrict__ den_part,
                float*       __restrict__ out,
                int B, int D, int K, int total)
{
    const int idx = blockIdx.x * 256 + threadIdx.x;
    if (idx >= total) return;
    const int d  = idx % D;
    const int bv = idx / D;
    const int b  = bv / VV;
    const int v  = bv - b * VV;

    float den = 1e-6f;
    float num = 0.0f;
    for (int k = 0; k < K; ++k) {
        den += den_part[((size_t)b * K + k) * VV + v];
        num += num_part[(((size_t)b * K + k) * VV + v) * (size_t)D + d];
    }
    out[idx] = num / den;
}

extern "C" void kernel_launch(void* const* d_in, const int* in_sizes, int n_in,
                              void* d_out, int out_size, void* d_ws, size_t ws_size,
                              hipStream_t stream)
{
    const float* v_pad     = (const float*)d_in[0];
    const int*   v_len     = (const int*)d_in[1];
    const int*   grid_thws = (const int*)d_in[2];
    const float* centers   = (const float*)d_in[3];
    float*       out       = (float*)d_out;

    const int B = in_sizes[1];
    const int V = VV;
    const int D = out_size / (B * V);
    const int L = in_sizes[0] / (B * D);

    int K = 8;
    const size_t per_k = ((size_t)B * V * D + (size_t)B * V) * sizeof(float);
    while (K > 1 && (size_t)K * per_k > ws_size) K >>= 1;

    float* num_part = (float*)d_ws;
    float* den_part = num_part + (size_t)B * K * V * D;

    dim3 grid1(K, D / DC, B);
    dvs_mfma<<<grid1, NTH, 0, stream>>>(v_pad, v_len, grid_thws, centers,
                                        num_part, den_part, B, L, D, K);

    const int total = B * V * D;
    dvs_reduce<<<(total + 255) / 256, 256, 0, stream>>>(num_part, den_part, out,
                                                        B, D, K, total);
}

// Round 4
// 43.298 us; speedup vs baseline: 3.9344x; 1.2146x over previous
//
#include <hip/hip_runtime.h>
#include <math.h>
#include <stdint.h>

// DynamicViewSampler — bf16 MFMA, pipelined staging.
// A = m (V=64 x K) packed into fragment order in LDS (plain b128 reads).
// B = v_pad tile staged row-major [l][d] bf16, stride ST=134 (conflict-free
//     u16 fragment gather: 4*ST mod 32 banks = 24 -> octets at {0,24,16,8}).
// Cross-tile prefetch: tile t+1 global loads issued before tile t's MFMA.
// DC=128 -> 1024 blocks -> 4 blocks/CU for latency hiding.

constexpr int VV      = 64;    // views (M)
constexpr int DC      = 128;   // D cols per block (N)
constexpr int KS      = 64;    // L rows per tile (two K=32 MFMA steps)
constexpr int NTH     = 256;
constexpr int ST      = 134;   // smB row stride in bf16 units
constexpr int SXY_MAX = 512;

typedef __attribute__((ext_vector_type(8))) short short8;
typedef __attribute__((ext_vector_type(4))) float f32x4;

static __device__ __forceinline__ unsigned short f2bf(float f) {
    unsigned u = __builtin_bit_cast(unsigned, f);
    u += 0x7fffu + ((u >> 16) & 1u);          // RNE
    return (unsigned short)(u >> 16);
}

__global__ __launch_bounds__(NTH)
void dvs_mfma(const float* __restrict__ v_pad, const int* __restrict__ v_len,
              const int* __restrict__ grid_thws, const float* __restrict__ centers,
              float* __restrict__ num_part,   // [B][K][V][D]
              float* __restrict__ den_part,   // [B][K][V]
              int B, int L, int D, int K)
{
    const int kblk = blockIdx.x, dcb = blockIdx.y, b = blockIdx.z;
    const int tid  = threadIdx.x;
    const int d0   = dcb * DC;
    const int lane = tid & 63;
    const int wave = tid >> 6;

    __shared__ __align__(16) unsigned short smA[512 * 8];   // 8 KB
    __shared__ __align__(16) unsigned short smB[KS][ST];    // ~16.75 KB
    __shared__ float2 sxy[SXY_MAX];                          // 4 KB
    __shared__ float  sden[4][VV];                           // 1 KB

    // ---- geometry (exact f32 replication of reference) ----
    const int   Lv = v_len[b];
    const float Hf = (float)grid_thws[b*3 + 1];
    const float Wf = (float)grid_thws[b*3 + 2];
    const float sq = sqrtf((float)Lv * (Wf / Hf));
    int W_eff = (int)rintf(sq);                       if (W_eff < 1) W_eff = 1;
    int H_eff = (int)ceilf((float)Lv / (float)W_eff); if (H_eff < 1) H_eff = 1;
    const float invW = 1.f / (float)W_eff, invH = 1.f / (float)H_eff;

    const int chunk = (Lv + K - 1) / K;
    const int l0 = kblk * chunk;
    const int l1 = min(l0 + chunk, Lv);

    // ---- A-compute role ----
    const int    av  = tid & 63;
    const int    aq  = tid >> 6;
    const float2 ctr = ((const float2*)centers)[(size_t)b * VV + av];
    const int    amf = av >> 4, ar = av & 15;
    float denacc = 0.f;

    // ---- B-staging role: 32 float4 cols x 8 row-groups ----
    const int sd   = tid & 31;
    const int srow = tid >> 5;

    // ---- fragment-read role ----
    const int fcol = lane & 15, foct = lane >> 4;

    f32x4 acc[4][2];
#pragma unroll
    for (int i = 0; i < 4; ++i) {
        acc[i][0] = f32x4{0.f, 0.f, 0.f, 0.f};
        acc[i][1] = f32x4{0.f, 0.f, 0.f, 0.f};
    }

    const float* vp_b = v_pad + (size_t)b * L * D + d0;

    for (int st = l0; st < l1; st += SXY_MAX) {
        const int st1 = min(st + SXY_MAX, l1);
        __syncthreads();                       // prior users of sxy/smB done

        // prologue: issue first tile's loads, then fill sxy under their latency
        float4 ld[8];
#pragma unroll
        for (int it = 0; it < 8; ++it) {
            const int l = st + it * 8 + srow;
            ld[it] = make_float4(0.f, 0.f, 0.f, 0.f);
            if (l < st1)
                ld[it] = *(const float4*)(vp_b + (size_t)l * D + sd * 4);
        }
        for (int i = tid; i < st1 - st; i += NTH) {
            const int l   = st + i;
            const int row = l / W_eff;
            const int col = l - row * W_eff;
            sxy[i] = make_float2((float)col * invW, (float)row * invH);
        }
        __syncthreads();                       // sxy visible

        for (int lt = st; lt < st1; lt += KS) {
            // ---- stage B (waits on ld issued last iteration / prologue) ----
#pragma unroll
            for (int it = 0; it < 8; ++it) {
                const int lrow = it * 8 + srow;
                unsigned* w = (unsigned*)&smB[lrow][sd * 4];
                w[0] = (unsigned)f2bf(ld[it].x) | ((unsigned)f2bf(ld[it].y) << 16);
                w[1] = (unsigned)f2bf(ld[it].z) | ((unsigned)f2bf(ld[it].w) << 16);
            }
            // ---- stage A: m packed into fragment order ----
#pragma unroll
            for (int ks = 0; ks < 2; ++ks) {
                union { unsigned short h[8]; short8 s; } ap;
#pragma unroll
                for (int j = 0; j < 8; ++j) {
                    const int kl = ks * 32 + aq * 8 + j;
                    const int l  = lt + kl;
                    float m = 0.f;
                    if (l < st1) {
                        const float2 xy = sxy[(lt - st) + kl];
                        const float dx = ctr.x - xy.x, dy = ctr.y - xy.y;
                        m = __expf(-20.f * (dx * dx + dy * dy));
                    }
                    denacc += m;
                    ap.h[j] = f2bf(m);
                }
                ((short8*)smA)[(ks * 4 + amf) * 64 + aq * 16 + ar] = ap.s;
            }
            __syncthreads();                   // tile staged

            // ---- prefetch next tile's globals (fly under MFMA phase) ----
            const int ltn = lt + KS;
            if (ltn < st1) {
#pragma unroll
                for (int it = 0; it < 8; ++it) {
                    const int l = ltn + it * 8 + srow;
                    ld[it] = make_float4(0.f, 0.f, 0.f, 0.f);
                    if (l < st1)
                        ld[it] = *(const float4*)(vp_b + (size_t)l * D + sd * 4);
                }
            }

            // ---- MFMA: 2 k-halves x 4 m-frags x 2 n-frags ----
#pragma unroll
            for (int ks = 0; ks < 2; ++ks) {
                short8 af[4];
#pragma unroll
                for (int mf = 0; mf < 4; ++mf)
                    af[mf] = ((const short8*)smA)[(ks * 4 + mf) * 64 + lane];

#pragma unroll
                for (int nf = 0; nf < 2; ++nf) {
                    const int colx  = wave * 32 + nf * 16 + fcol;
                    const int kbase = ks * 32 + foct * 8;
                    union { unsigned short h[8]; short8 s; } bf;
#pragma unroll
                    for (int j = 0; j < 8; ++j)
                        bf.h[j] = smB[kbase + j][colx];
#pragma unroll
                    for (int mf = 0; mf < 4; ++mf)
                        acc[mf][nf] = __builtin_amdgcn_mfma_f32_16x16x32_bf16(
                            af[mf], bf.s, acc[mf][nf], 0, 0, 0);
                }
            }
            __syncthreads();                   // MFMA reads done; smB reusable
        }
    }

    // ---- denominator reduce (deterministic) ----
    sden[aq][av] = denacc;
    __syncthreads();
    if (dcb == 0 && tid < VV) {
        den_part[((size_t)b * K + kblk) * VV + tid] =
            sden[0][tid] + sden[1][tid] + sden[2][tid] + sden[3][tid];
    }

    // ---- numerator partials (C/D: col=lane&15, row=(lane>>4)*4+r) ----
    float* basep = num_part + ((size_t)b * K + kblk) * VV * (size_t)D + d0 + wave * 32;
#pragma unroll
    for (int mf = 0; mf < 4; ++mf) {
#pragma unroll
        for (int nf = 0; nf < 2; ++nf) {
            const int colx = nf * 16 + fcol;
            const int row0 = mf * 16 + foct * 4;
#pragma unroll
            for (int r = 0; r < 4; ++r)
                basep[(size_t)(row0 + r) * D + colx] = acc[mf][nf][r];
        }
    }
}

__global__ __launch_bounds__(256)
void dvs_reduce(const float* __restrict__ num_part,
                const float* __restrict__ den_part,
                float*       __restrict__ out,
                int B, int D, int K, int total4)
{
    const int idx = blockIdx.x * 256 + threadIdx.x;
    if (idx >= total4) return;
    const int dq4 = D / 4;
    const int d4  = idx % dq4;
    const int bv  = idx / dq4;
    const int b   = bv / VV;
    const int v   = bv - b * VV;

    float  den = 1e-6f;
    float4 num = make_float4(0.f, 0.f, 0.f, 0.f);
    for (int k = 0; k < K; ++k) {
        den += den_part[((size_t)b * K + k) * VV + v];
        const float4 p = ((const float4*)(num_part +
                          (((size_t)b * K + k) * VV + v) * (size_t)D))[d4];
        num.x += p.x; num.y += p.y; num.z += p.z; num.w += p.w;
    }
    const float inv = 1.0f / den;
    float4 o = make_float4(num.x * inv, num.y * inv, num.z * inv, num.w * inv);
    ((float4*)out)[(size_t)bv * dq4 + d4] = o;
}

extern "C" void kernel_launch(void* const* d_in, const int* in_sizes, int n_in,
                              void* d_out, int out_size, void* d_ws, size_t ws_size,
                              hipStream_t stream)
{
    const float* v_pad     = (const float*)d_in[0];
    const int*   v_len     = (const int*)d_in[1];
    const int*   grid_thws = (const int*)d_in[2];
    const float* centers   = (const float*)d_in[3];
    float*       out       = (float*)d_out;

    const int B = in_sizes[1];
    const int V = VV;
    const int D = out_size / (B * V);
    const int L = in_sizes[0] / (B * D);

    int K = 8;
    const size_t per_k = ((size_t)B * V * D + (size_t)B * V) * sizeof(float);
    while (K > 1 && (size_t)K * per_k > ws_size) K >>= 1;

    float* num_part = (float*)d_ws;
    float* den_part = num_part + (size_t)B * K * V * D;

    dim3 grid1(K, D / DC, B);
    dvs_mfma<<<grid1, NTH, 0, stream>>>(v_pad, v_len, grid_thws, centers,
                                        num_part, den_part, B, L, D, K);

    const int total4 = B * V * D / 4;
    dvs_reduce<<<(total4 + 255) / 256, 256, 0, stream>>>(num_part, den_part, out,
                                                         B, D, K, total4);
}